// Round 2
// baseline (1719.109 us; speedup 1.0000x reference)
//
#include <hip/hip_runtime.h>

#define NFFT 4096
#define LOGN 12
#define NT   256
#define SIG  2048
#define NSCALES 64
#define LMAX 1025
#define NBATCH 512

// ---------------------------------------------------------------------------
// Twiddle table: tw[k] = e^{+2*pi*i*k/NFFT}, k in [0, NFFT/2)
// ---------------------------------------------------------------------------
__global__ void twiddle_init(float2* __restrict__ tw) {
    int k = blockIdx.x * blockDim.x + threadIdx.x;
    if (k < NFFT / 2) {
        float s, c;
        sincospif(k / (float)(NFFT / 2), &s, &c);  // angle = pi*k/(N/2) = 2*pi*k/N
        tw[k] = make_float2(c, s);
    }
}

// ---------------------------------------------------------------------------
// In-LDS radix-2 DIF forward FFT (natural input -> bit-reversed output).
// Twiddle sign: e^{-2*pi*i*j/len} = conj(tw[j * N/len]).
// ---------------------------------------------------------------------------
__device__ __forceinline__ void dif_forward(float* re, float* im,
                                            const float* twr, const float* twi,
                                            int tid) {
    for (int st = LOGN; st >= 1; --st) {
        int half = 1 << (st - 1);
        int twsh = LOGN - st;
        __syncthreads();
        for (int idx = tid; idx < NFFT / 2; idx += NT) {
            int j  = idx & (half - 1);
            int i0 = ((idx >> (st - 1)) << st) + j;
            int i1 = i0 + half;
            float ur = re[i0], ui = im[i0];
            float vr = re[i1], vi = im[i1];
            re[i0] = ur + vr;
            im[i0] = ui + vi;
            float dr = ur - vr, di = ui - vi;
            float wr = twr[j << twsh], wi = -twi[j << twsh];
            re[i1] = dr * wr - di * wi;
            im[i1] = dr * wi + di * wr;
        }
    }
    __syncthreads();
}

// ---------------------------------------------------------------------------
// Forward FFT of signals: Xf[b][p] = DFT(x_b zero-padded)[bitrev(p)]
// ---------------------------------------------------------------------------
__global__ __launch_bounds__(NT) void fwd_fft_x(const float* __restrict__ x,
                                                const float2* __restrict__ twg,
                                                float2* __restrict__ Xf) {
    __shared__ float re[NFFT], im[NFFT];
    __shared__ float twr[NFFT / 2], twi[NFFT / 2];
    int tid = threadIdx.x;
    int b   = blockIdx.x;
    for (int i = tid; i < NFFT / 2; i += NT) {
        float2 t = twg[i];
        twr[i] = t.x; twi[i] = t.y;
    }
    for (int i = tid; i < NFFT; i += NT) {
        re[i] = (i < SIG) ? x[b * SIG + i] : 0.0f;
        im[i] = 0.0f;
    }
    dif_forward(re, im, twr, twi, tid);
    for (int p = tid; p < NFFT; p += NT)
        Xf[(size_t)b * NFFT + p] = make_float2(re[p], im[p]);
}

// ---------------------------------------------------------------------------
// Forward FFT of filters, with diff + irfft-normalization + (-sqrt(scale))
// folded in:  Kf[s][p] = DFT(K_s)[k] * (e^{2 pi i k/N} - 1) * (-ssq[s]/N),
// where k = bitrev(p).
// ---------------------------------------------------------------------------
__global__ __launch_bounds__(NT) void fwd_fft_k(const float* __restrict__ ker,
                                                const float* __restrict__ ssq,
                                                const float2* __restrict__ twg,
                                                float2* __restrict__ Kf) {
    __shared__ float re[NFFT], im[NFFT];
    __shared__ float twr[NFFT / 2], twi[NFFT / 2];
    int tid = threadIdx.x;
    int s   = blockIdx.x;
    for (int i = tid; i < NFFT / 2; i += NT) {
        float2 t = twg[i];
        twr[i] = t.x; twi[i] = t.y;
    }
    for (int i = tid; i < NFFT; i += NT) {
        re[i] = (i < LMAX) ? ker[s * LMAX + i] : 0.0f;
        im[i] = 0.0f;
    }
    dif_forward(re, im, twr, twi, tid);
    float scale = -ssq[s] * (1.0f / (float)NFFT);
    for (int p = tid; p < NFFT; p += NT) {
        int k = (int)(__brev((unsigned)p) >> (32 - LOGN));
        float sn, cs;
        sincospif(k / (float)(NFFT / 2), &sn, &cs);  // e^{2 pi i k / N}
        float fr = scale * (cs - 1.0f);
        float fi = scale * sn;
        float zr = re[p], zi = im[p];
        Kf[(size_t)s * NFFT + p] = make_float2(zr * fr - zi * fi,
                                               zr * fi + zi * fr);
    }
}

// ---------------------------------------------------------------------------
// Per-(b,s): pointwise product (bit-reversed order) + radix-2 DIT inverse FFT
// (bit-reversed input -> natural output) + trimmed store.
// z[t] = -ssq[s] * (conv[t+1] - conv[t]);  out[b,s,n] = z[start_s + n].
// ---------------------------------------------------------------------------
__global__ __launch_bounds__(NT) void conv_ifft(const float2* __restrict__ Xf,
                                                const float2* __restrict__ Kf,
                                                const int* __restrict__ trim,
                                                const float2* __restrict__ twg,
                                                float* __restrict__ out) {
    __shared__ float re[NFFT], im[NFFT];
    __shared__ float twr[NFFT / 2], twi[NFFT / 2];
    int tid = threadIdx.x;
    int b   = blockIdx.x >> 6;
    int s   = blockIdx.x & 63;

    for (int i = tid; i < NFFT / 2; i += NT) {
        float2 t = twg[i];
        twr[i] = t.x; twi[i] = t.y;
    }
    const float2* xrow = Xf + (size_t)b * NFFT;
    const float2* krow = Kf + (size_t)s * NFFT;
    for (int p = tid; p < NFFT; p += NT) {
        float2 xf = xrow[p];
        float2 kf = krow[p];
        re[p] = xf.x * kf.x - xf.y * kf.y;
        im[p] = xf.x * kf.y + xf.y * kf.x;
    }

    for (int st = 1; st <= LOGN; ++st) {
        int half = 1 << (st - 1);
        int twsh = LOGN - st;
        __syncthreads();
        for (int idx = tid; idx < NFFT / 2; idx += NT) {
            int j  = idx & (half - 1);
            int i0 = ((idx >> (st - 1)) << st) + j;
            int i1 = i0 + half;
            float wr = twr[j << twsh], wi = twi[j << twsh];
            float tr = re[i1], ti = im[i1];
            float vr = tr * wr - ti * wi;
            float vi = tr * wi + ti * wr;
            float ur = re[i0], ui = im[i0];
            re[i0] = ur + vr;
            im[i0] = ui + vi;
            re[i1] = ur - vr;
            im[i1] = ui - vi;
        }
    }
    __syncthreads();

    int start = trim[s * SIG];                    // trim indices are start+n
    float* orow = out + (size_t)blockIdx.x * SIG; // (b*64+s)*2048
    for (int n = tid; n < SIG; n += NT)
        orow[n] = re[start + n];
}

// ---------------------------------------------------------------------------
extern "C" void kernel_launch(void* const* d_in, const int* in_sizes, int n_in,
                              void* d_out, int out_size, void* d_ws, size_t ws_size,
                              hipStream_t stream) {
    const float* x    = (const float*)d_in[0];
    const float* ker  = (const float*)d_in[1];
    const float* ssq  = (const float*)d_in[2];
    const int*   trim = (const int*)d_in[3];
    float*       out  = (float*)d_out;

    float2* tw = (float2*)d_ws;                        // 2048 float2
    float2* Xf = tw + NFFT / 2;                        // 512*4096 float2
    float2* Kf = Xf + (size_t)NBATCH * NFFT;           // 64*4096 float2

    hipLaunchKernelGGL(twiddle_init, dim3((NFFT / 2 + 255) / 256), dim3(256), 0, stream, tw);
    hipLaunchKernelGGL(fwd_fft_x, dim3(NBATCH), dim3(NT), 0, stream, x, tw, Xf);
    hipLaunchKernelGGL(fwd_fft_k, dim3(NSCALES), dim3(NT), 0, stream, ker, ssq, tw, Kf);
    hipLaunchKernelGGL(conv_ifft, dim3(NBATCH * NSCALES), dim3(NT), 0, stream,
                       Xf, Kf, trim, tw, out);
}

// Round 4
// 495.356 us; speedup vs baseline: 3.4705x; 3.4705x over previous
//
#include <hip/hip_runtime.h>

#define NFFT 4096
#define SIG  2048
#define NSCALES 64
#define LMAX 1025
#define NBATCH 512
#define NT   256

// XOR swizzle on complex index: spreads strided Stockham writes across banks.
// Even XOR value preserves pair adjacency (swz(2j+1) == swz(2j)+1).
__device__ __forceinline__ int swz(int a) { return a ^ ((a >> 4) & 14); }

__device__ __forceinline__ float2 cmul(float2 a, float2 b) {
    return make_float2(a.x * b.x - a.y * b.y, a.x * b.y + a.y * b.x);
}

// ---------------------------------------------------------------------------
// One Stockham radix-4 stage: src -> dst.  NN = total size, G = NN/4 = L*M.
// Reads  src[g + q*G]            (g = j*M + k, consecutive -> conflict-free)
// Writes dst[k + 4*j*M + r*M]    (swizzled -> ~conflict-free)
// Twiddle e^{DIR*2*pi*i*j*r/(4L)}; DIR=-1 forward, +1 inverse.
// ---------------------------------------------------------------------------
template <int L, int M, int DIR, int NN>
__device__ __forceinline__ void r4_stage(const float2* __restrict__ src,
                                         float2* __restrict__ dst, int tid) {
    const int G = NN / 4;  // == L*M
    #pragma unroll
    for (int g0 = 0; g0 < G; g0 += NT) {
        int g = g0 + tid;
        int k = g & (M - 1);
        int j = g / M;
        float2 a0 = src[swz(g)];
        float2 a1 = src[swz(g + G)];
        float2 a2 = src[swz(g + 2 * G)];
        float2 a3 = src[swz(g + 3 * G)];
        float2 t0 = make_float2(a0.x + a2.x, a0.y + a2.y);
        float2 t1 = make_float2(a0.x - a2.x, a0.y - a2.y);
        float2 t2 = make_float2(a1.x + a3.x, a1.y + a3.y);
        float2 t3 = make_float2(a1.x - a3.x, a1.y - a3.y);
        float2 jt3 = make_float2(-(float)DIR * t3.y, (float)DIR * t3.x);  // DIR*i*t3
        float2 b0 = make_float2(t0.x + t2.x, t0.y + t2.y);
        float2 b2 = make_float2(t0.x - t2.x, t0.y - t2.y);
        float2 b1 = make_float2(t1.x + jt3.x, t1.y + jt3.y);
        float2 b3 = make_float2(t1.x - jt3.x, t1.y - jt3.y);
        float sw, cw;
        sincospif((float)DIR * (float)j * (1.0f / (2 * L)), &sw, &cw);
        float2 w1 = make_float2(cw, sw);
        float2 w2 = make_float2(cw * cw - sw * sw, 2.0f * cw * sw);
        float2 w3 = cmul(w1, w2);
        b1 = cmul(b1, w1);
        b2 = cmul(b2, w2);
        b3 = cmul(b3, w3);
        int base = k + 4 * j * M;
        dst[swz(base)]         = b0;
        dst[swz(base + M)]     = b1;
        dst[swz(base + 2 * M)] = b2;
        dst[swz(base + 3 * M)] = b3;
    }
}

// ---------------------------------------------------------------------------
// Forward FFT (size 4096, Stockham radix-4 x6, natural order in and out) of
// one real signal per workgroup.  Xf[b][k] = DFT(x_b zero-padded)[k].
// ---------------------------------------------------------------------------
__global__ __launch_bounds__(NT, 2) void fwd_fft_x(const float* __restrict__ x,
                                                   float2* __restrict__ Xf) {
    __shared__ float2 bufA[NFFT], bufB[NFFT];
    int tid = threadIdx.x;
    int b = blockIdx.x;
    #pragma unroll
    for (int i0 = 0; i0 < NFFT; i0 += NT) {
        int i = i0 + tid;
        float vr = (i < SIG) ? x[(size_t)b * SIG + i] : 0.0f;
        bufA[swz(i)] = make_float2(vr, 0.0f);
    }
    __syncthreads();
    r4_stage<1024, 1, -1, 4096>(bufA, bufB, tid); __syncthreads();
    r4_stage<256, 4, -1, 4096>(bufB, bufA, tid); __syncthreads();
    r4_stage<64, 16, -1, 4096>(bufA, bufB, tid); __syncthreads();
    r4_stage<16, 64, -1, 4096>(bufB, bufA, tid); __syncthreads();
    r4_stage<4, 256, -1, 4096>(bufA, bufB, tid); __syncthreads();
    r4_stage<1, 1024, -1, 4096>(bufB, bufA, tid); __syncthreads();
    float2* Xrow = Xf + (size_t)b * NFFT;
    #pragma unroll
    for (int i0 = 0; i0 < NFFT; i0 += NT) {
        int i = i0 + tid;
        Xrow[i] = bufA[swz(i)];
    }
}

// ---------------------------------------------------------------------------
// Forward FFT of filters with diff + irfft 1/N + (-sqrt(scale)) folded in:
// Kf[s][k] = DFT(K_s)[k] * (e^{2 pi i k/4096} - 1) * (-ssq[s] / 4096).
// ---------------------------------------------------------------------------
__global__ __launch_bounds__(NT, 2) void fwd_fft_k(const float* __restrict__ ker,
                                                   const float* __restrict__ ssq,
                                                   float2* __restrict__ Kf) {
    __shared__ float2 bufA[NFFT], bufB[NFFT];
    int tid = threadIdx.x;
    int s = blockIdx.x;
    #pragma unroll
    for (int i0 = 0; i0 < NFFT; i0 += NT) {
        int i = i0 + tid;
        float vr = (i < LMAX) ? ker[(size_t)s * LMAX + i] : 0.0f;
        bufA[swz(i)] = make_float2(vr, 0.0f);
    }
    __syncthreads();
    r4_stage<1024, 1, -1, 4096>(bufA, bufB, tid); __syncthreads();
    r4_stage<256, 4, -1, 4096>(bufB, bufA, tid); __syncthreads();
    r4_stage<64, 16, -1, 4096>(bufA, bufB, tid); __syncthreads();
    r4_stage<16, 64, -1, 4096>(bufB, bufA, tid); __syncthreads();
    r4_stage<4, 256, -1, 4096>(bufA, bufB, tid); __syncthreads();
    r4_stage<1, 1024, -1, 4096>(bufB, bufA, tid); __syncthreads();
    float scale = -ssq[s] * (1.0f / (float)NFFT);
    float2* Krow = Kf + (size_t)s * NFFT;
    #pragma unroll
    for (int i0 = 0; i0 < NFFT; i0 += NT) {
        int i = i0 + tid;
        float sn, cs;
        sincospif((float)i * (1.0f / 2048.0f), &sn, &cs);  // e^{2 pi i k/4096}
        float2 fac = make_float2(scale * (cs - 1.0f), scale * sn);
        Krow[i] = cmul(bufA[swz(i)], fac);
    }
}

// ---------------------------------------------------------------------------
// Per-(b,s): P[k] = X[k]*Khat[k].  Real-ifft packing with FULL spectrum:
//   Q[k'] = (P[k'] + P[k'+2048]) + i*t*(P[k'] - P[k'+2048]),  t = e^{2pi i k'/4096}
// (no 1/2 factor -- that belongs to the half-spectrum conjugate variant).
// Then fused register radix-2 stage + 5 Stockham radix-4 inverse stages
// (size 2048).  Z[m] = z[2m] + i z[2m+1];  out[n] = z[start+n].
// ---------------------------------------------------------------------------
__global__ __launch_bounds__(NT, 4) void conv_ifft(const float2* __restrict__ Xf,
                                                   const float2* __restrict__ Kf,
                                                   const int* __restrict__ trim,
                                                   float* __restrict__ out) {
    __shared__ float2 bufA[2048], bufB[2048];
    int tid = threadIdx.x;
    int b = blockIdx.x >> 6;
    int s = blockIdx.x & 63;
    const float2* X = Xf + (size_t)b * NFFT;
    const float2* K = Kf + (size_t)s * NFFT;

    for (int j0 = 0; j0 < 1024; j0 += NT) {
        int j = j0 + tid;
        float2 P0 = cmul(X[j], K[j]);
        float2 P1 = cmul(X[j + 1024], K[j + 1024]);
        float2 P2 = cmul(X[j + 2048], K[j + 2048]);
        float2 P3 = cmul(X[j + 3072], K[j + 3072]);
        float sj, cj;
        sincospif((float)j * (1.0f / 2048.0f), &sj, &cj);  // t = e^{2 pi i j/4096}
        // Q[j] = (P0+P2) + i*t*(P0-P2)
        float2 d02 = make_float2(P0.x - P2.x, P0.y - P2.y);
        float2 itd = cmul(make_float2(-sj, cj), d02);       // (i*t)*d02
        float2 Qa = make_float2(P0.x + P2.x + itd.x,
                                P0.y + P2.y + itd.y);
        // Q[j+1024] = (P1+P3) - t*(P1-P3)   (t_{j+1024} = i*t_j)
        float2 d13 = make_float2(P1.x - P3.x, P1.y - P3.y);
        float2 td = cmul(make_float2(cj, sj), d13);
        float2 Qb = make_float2(P1.x + P3.x - td.x,
                                P1.y + P3.y - td.y);
        // fused radix-2 stage (l=1024, m=1): w = e^{+2 pi i j/2048} = t^2
        float2 u = make_float2(Qa.x + Qb.x, Qa.y + Qb.y);
        float2 dq = make_float2(Qa.x - Qb.x, Qa.y - Qb.y);
        float2 w2 = make_float2(cj * cj - sj * sj, 2.0f * cj * sj);
        float2 v = cmul(dq, w2);
        int p = swz(2 * j);  // even; swz(2j+1) == p+1
        bufA[p] = u;
        bufA[p + 1] = v;
    }
    __syncthreads();
    r4_stage<256, 2, +1, 2048>(bufA, bufB, tid); __syncthreads();
    r4_stage<64, 8, +1, 2048>(bufB, bufA, tid); __syncthreads();
    r4_stage<16, 32, +1, 2048>(bufA, bufB, tid); __syncthreads();
    r4_stage<4, 128, +1, 2048>(bufB, bufA, tid); __syncthreads();
    r4_stage<1, 512, +1, 2048>(bufA, bufB, tid); __syncthreads();

    int start = trim[s * SIG];
    const float* f = (const float*)bufB;   // f view: z[2m], z[2m+1] at swz(m)
    float* orow = out + (size_t)blockIdx.x * SIG;
    for (int n0 = 0; n0 < SIG; n0 += NT) {
        int n = n0 + tid;
        int t = start + n;
        orow[n] = f[2 * swz(t >> 1) + (t & 1)];
    }
}

// ---------------------------------------------------------------------------
extern "C" void kernel_launch(void* const* d_in, const int* in_sizes, int n_in,
                              void* d_out, int out_size, void* d_ws, size_t ws_size,
                              hipStream_t stream) {
    const float* x    = (const float*)d_in[0];
    const float* ker  = (const float*)d_in[1];
    const float* ssq  = (const float*)d_in[2];
    const int*   trim = (const int*)d_in[3];
    float*       out  = (float*)d_out;

    float2* Xf = (float2*)d_ws;                       // 512*4096 float2 = 16 MB
    float2* Kf = Xf + (size_t)NBATCH * NFFT;          // 64*4096 float2 = 2 MB

    hipLaunchKernelGGL(fwd_fft_x, dim3(NBATCH), dim3(NT), 0, stream, x, Xf);
    hipLaunchKernelGGL(fwd_fft_k, dim3(NSCALES), dim3(NT), 0, stream, ker, ssq, Kf);
    hipLaunchKernelGGL(conv_ifft, dim3(NBATCH * NSCALES), dim3(NT), 0, stream,
                       Xf, Kf, trim, out);
}

// Round 5
// 466.609 us; speedup vs baseline: 3.6843x; 1.0616x over previous
//
#include <hip/hip_runtime.h>

#define NFFT 4096
#define SIG  2048
#define NSCALES 64
#define LMAX 1025
#define NBATCH 512
#define NT   256

// XOR swizzle on complex index: spreads strided Stockham writes across banks.
// Even XOR value preserves pair adjacency (swz(2j+1) == swz(2j)+1).
__device__ __forceinline__ int swz(int a) { return a ^ ((a >> 4) & 14); }

__device__ __forceinline__ float2 cmul(float2 a, float2 b) {
    return make_float2(a.x * b.x - a.y * b.y, a.x * b.y + a.y * b.x);
}

// ---------------------------------------------------------------------------
// Twiddle tables (global, L1/L2-resident, shared by all 32768 conv WGs):
//   TQ[j]  = (cos, sin, cos, sin) of (pi*j/2048, pi*j/1024):  t and t^2,
//            t = e^{2 pi i j/4096}, j in [0,1024).                 16 KB
//   TW[..] = per-stage (w1, w2, w3) for inverse Stockham radix-4 stages
//            (DIR=+1), padded to 32 B (2 x float4).  Stage offsets (in
//            entries): L=256 -> 0, L=64 -> 256, L=16 -> 320, L=4 -> 336.
//            w_r = e^{+2 pi i j r/(4L)}.                           11 KB
// ---------------------------------------------------------------------------
#define TW_ENTRIES 340

__global__ void twiddle_init(float4* __restrict__ TQ, float4* __restrict__ TW) {
    int i = blockIdx.x * blockDim.x + threadIdx.x;
    if (i < 1024) {
        float s1, c1, s2, c2;
        sincospif(i / 2048.0f, &s1, &c1);
        sincospif(i / 1024.0f, &s2, &c2);
        TQ[i] = make_float4(c1, s1, c2, s2);
    } else if (i < 1024 + TW_ENTRIES) {
        int idx = i - 1024;
        int L, j;
        if (idx < 256)      { L = 256; j = idx; }
        else if (idx < 320) { L = 64;  j = idx - 256; }
        else if (idx < 336) { L = 16;  j = idx - 320; }
        else                { L = 4;   j = idx - 336; }
        float fL = (float)L, fj = (float)j;
        float s1, c1, s2, c2, s3, c3;
        sincospif(fj / (2.0f * fL), &s1, &c1);          // w1 = e^{+i pi j/(2L)}
        sincospif(fj / fL, &s2, &c2);                   // w2 = w1^2
        sincospif(3.0f * fj / (2.0f * fL), &s3, &c3);   // w3 = w1^3
        TW[2 * idx]     = make_float4(c1, s1, c2, s2);
        TW[2 * idx + 1] = make_float4(c3, s3, 0.0f, 0.0f);
    }
}

// ---------------------------------------------------------------------------
// Generic Stockham radix-4 stage with on-the-fly twiddles (used by the two
// small forward-FFT kernels only).  DIR=-1 forward.
// ---------------------------------------------------------------------------
template <int L, int M, int DIR, int NN>
__device__ __forceinline__ void r4_stage(const float2* __restrict__ src,
                                         float2* __restrict__ dst, int tid) {
    const int G = NN / 4;
    #pragma unroll
    for (int g0 = 0; g0 < G; g0 += NT) {
        int g = g0 + tid;
        int k = g & (M - 1);
        int j = g / M;
        float2 a0 = src[swz(g)];
        float2 a1 = src[swz(g + G)];
        float2 a2 = src[swz(g + 2 * G)];
        float2 a3 = src[swz(g + 3 * G)];
        float2 t0 = make_float2(a0.x + a2.x, a0.y + a2.y);
        float2 t1 = make_float2(a0.x - a2.x, a0.y - a2.y);
        float2 t2 = make_float2(a1.x + a3.x, a1.y + a3.y);
        float2 t3 = make_float2(a1.x - a3.x, a1.y - a3.y);
        float2 jt3 = make_float2(-(float)DIR * t3.y, (float)DIR * t3.x);
        float2 b0 = make_float2(t0.x + t2.x, t0.y + t2.y);
        float2 b2 = make_float2(t0.x - t2.x, t0.y - t2.y);
        float2 b1 = make_float2(t1.x + jt3.x, t1.y + jt3.y);
        float2 b3 = make_float2(t1.x - jt3.x, t1.y - jt3.y);
        float sw, cw;
        sincospif((float)DIR * (float)j * (1.0f / (2 * L)), &sw, &cw);
        float2 w1 = make_float2(cw, sw);
        float2 w2 = make_float2(cw * cw - sw * sw, 2.0f * cw * sw);
        float2 w3 = cmul(w1, w2);
        b1 = cmul(b1, w1);
        b2 = cmul(b2, w2);
        b3 = cmul(b3, w3);
        int base = k + 4 * j * M;
        dst[swz(base)]         = b0;
        dst[swz(base + M)]     = b1;
        dst[swz(base + 2 * M)] = b2;
        dst[swz(base + 3 * M)] = b3;
    }
}

// ---------------------------------------------------------------------------
// Inverse Stockham radix-4 stage (DIR=+1, NN=2048) with table twiddles.
// tw points at this stage's entries (2 x float4 per j).  L==1: w = 1.
// ---------------------------------------------------------------------------
template <int L, int M>
__device__ __forceinline__ void r4_stage_itab(const float2* __restrict__ src,
                                              float2* __restrict__ dst,
                                              const float4* __restrict__ tw,
                                              int tid) {
    const int G = 512;
    #pragma unroll
    for (int g0 = 0; g0 < G; g0 += NT) {
        int g = g0 + tid;
        int k = g & (M - 1);
        int j = g / M;
        float2 a0 = src[swz(g)];
        float2 a1 = src[swz(g + G)];
        float2 a2 = src[swz(g + 2 * G)];
        float2 a3 = src[swz(g + 3 * G)];
        float2 t0 = make_float2(a0.x + a2.x, a0.y + a2.y);
        float2 t1 = make_float2(a0.x - a2.x, a0.y - a2.y);
        float2 t2 = make_float2(a1.x + a3.x, a1.y + a3.y);
        float2 t3 = make_float2(a1.x - a3.x, a1.y - a3.y);
        float2 jt3 = make_float2(-t3.y, t3.x);            // +i * t3
        float2 b0 = make_float2(t0.x + t2.x, t0.y + t2.y);
        float2 b2 = make_float2(t0.x - t2.x, t0.y - t2.y);
        float2 b1 = make_float2(t1.x + jt3.x, t1.y + jt3.y);
        float2 b3 = make_float2(t1.x - jt3.x, t1.y - jt3.y);
        if (L > 1) {
            float4 wa = tw[2 * j];
            float4 wb = tw[2 * j + 1];
            b1 = cmul(b1, make_float2(wa.x, wa.y));
            b2 = cmul(b2, make_float2(wa.z, wa.w));
            b3 = cmul(b3, make_float2(wb.x, wb.y));
        }
        int base = k + 4 * j * M;
        dst[swz(base)]         = b0;
        dst[swz(base + M)]     = b1;
        dst[swz(base + 2 * M)] = b2;
        dst[swz(base + 3 * M)] = b3;
    }
}

// ---------------------------------------------------------------------------
// Forward FFT (size 4096, Stockham radix-4 x6, natural in/out), one real
// signal per workgroup.  Xf[b][k] = DFT(x_b zero-padded)[k].
// ---------------------------------------------------------------------------
__global__ __launch_bounds__(NT, 2) void fwd_fft_x(const float* __restrict__ x,
                                                   float2* __restrict__ Xf) {
    __shared__ float2 bufA[NFFT], bufB[NFFT];
    int tid = threadIdx.x;
    int b = blockIdx.x;
    #pragma unroll
    for (int i0 = 0; i0 < NFFT; i0 += NT) {
        int i = i0 + tid;
        float vr = (i < SIG) ? x[(size_t)b * SIG + i] : 0.0f;
        bufA[swz(i)] = make_float2(vr, 0.0f);
    }
    __syncthreads();
    r4_stage<1024, 1, -1, 4096>(bufA, bufB, tid); __syncthreads();
    r4_stage<256, 4, -1, 4096>(bufB, bufA, tid); __syncthreads();
    r4_stage<64, 16, -1, 4096>(bufA, bufB, tid); __syncthreads();
    r4_stage<16, 64, -1, 4096>(bufB, bufA, tid); __syncthreads();
    r4_stage<4, 256, -1, 4096>(bufA, bufB, tid); __syncthreads();
    r4_stage<1, 1024, -1, 4096>(bufB, bufA, tid); __syncthreads();
    float2* Xrow = Xf + (size_t)b * NFFT;
    #pragma unroll
    for (int i0 = 0; i0 < NFFT; i0 += NT) {
        int i = i0 + tid;
        Xrow[i] = bufA[swz(i)];
    }
}

// ---------------------------------------------------------------------------
// Forward FFT of filters with diff + irfft 1/N + (-sqrt(scale)) folded in:
// Kf[s][k] = DFT(K_s)[k] * (e^{2 pi i k/4096} - 1) * (-ssq[s] / 4096).
// ---------------------------------------------------------------------------
__global__ __launch_bounds__(NT, 2) void fwd_fft_k(const float* __restrict__ ker,
                                                   const float* __restrict__ ssq,
                                                   float2* __restrict__ Kf) {
    __shared__ float2 bufA[NFFT], bufB[NFFT];
    int tid = threadIdx.x;
    int s = blockIdx.x;
    #pragma unroll
    for (int i0 = 0; i0 < NFFT; i0 += NT) {
        int i = i0 + tid;
        float vr = (i < LMAX) ? ker[(size_t)s * LMAX + i] : 0.0f;
        bufA[swz(i)] = make_float2(vr, 0.0f);
    }
    __syncthreads();
    r4_stage<1024, 1, -1, 4096>(bufA, bufB, tid); __syncthreads();
    r4_stage<256, 4, -1, 4096>(bufB, bufA, tid); __syncthreads();
    r4_stage<64, 16, -1, 4096>(bufA, bufB, tid); __syncthreads();
    r4_stage<16, 64, -1, 4096>(bufB, bufA, tid); __syncthreads();
    r4_stage<4, 256, -1, 4096>(bufA, bufB, tid); __syncthreads();
    r4_stage<1, 1024, -1, 4096>(bufB, bufA, tid); __syncthreads();
    float scale = -ssq[s] * (1.0f / (float)NFFT);
    float2* Krow = Kf + (size_t)s * NFFT;
    #pragma unroll
    for (int i0 = 0; i0 < NFFT; i0 += NT) {
        int i = i0 + tid;
        float sn, cs;
        sincospif((float)i * (1.0f / 2048.0f), &sn, &cs);  // e^{2 pi i k/4096}
        float2 fac = make_float2(scale * (cs - 1.0f), scale * sn);
        Krow[i] = cmul(bufA[swz(i)], fac);
    }
}

// ---------------------------------------------------------------------------
// Per-(b,s): P[k] = X[k]*Khat[k].  Real-ifft packing with FULL spectrum:
//   Q[k'] = (P[k'] + P[k'+2048]) + i*t*(P[k'] - P[k'+2048]),  t = e^{2pi i k'/4096}
// Then fused register radix-2 stage + 5 table-twiddle Stockham radix-4
// inverse stages (size 2048).  Z[m] = z[2m] + i z[2m+1]; out[n] = z[start+n].
// ---------------------------------------------------------------------------
__global__ __launch_bounds__(NT, 4) void conv_ifft(const float2* __restrict__ Xf,
                                                   const float2* __restrict__ Kf,
                                                   const int* __restrict__ trim,
                                                   const float4* __restrict__ TQ,
                                                   const float4* __restrict__ TW,
                                                   float* __restrict__ out) {
    __shared__ float2 bufA[2048], bufB[2048];
    int tid = threadIdx.x;
    int b = blockIdx.x >> 6;
    int s = blockIdx.x & 63;
    const float2* X = Xf + (size_t)b * NFFT;
    const float2* K = Kf + (size_t)s * NFFT;

    #pragma unroll
    for (int j0 = 0; j0 < 1024; j0 += NT) {
        int j = j0 + tid;
        float2 P0 = cmul(X[j], K[j]);
        float2 P1 = cmul(X[j + 1024], K[j + 1024]);
        float2 P2 = cmul(X[j + 2048], K[j + 2048]);
        float2 P3 = cmul(X[j + 3072], K[j + 3072]);
        float4 tq = TQ[j];                 // (t, t^2), t = e^{2 pi i j/4096}
        float cj = tq.x, sj = tq.y;
        // Q[j] = (P0+P2) + i*t*(P0-P2)
        float2 d02 = make_float2(P0.x - P2.x, P0.y - P2.y);
        float2 itd = cmul(make_float2(-sj, cj), d02);       // (i*t)*d02
        float2 Qa = make_float2(P0.x + P2.x + itd.x,
                                P0.y + P2.y + itd.y);
        // Q[j+1024] = (P1+P3) - t*(P1-P3)   (t_{j+1024} = i*t_j)
        float2 d13 = make_float2(P1.x - P3.x, P1.y - P3.y);
        float2 td = cmul(make_float2(cj, sj), d13);
        float2 Qb = make_float2(P1.x + P3.x - td.x,
                                P1.y + P3.y - td.y);
        // fused radix-2 stage (l=1024, m=1): w = e^{+2 pi i j/2048} = t^2
        float2 u = make_float2(Qa.x + Qb.x, Qa.y + Qb.y);
        float2 dq = make_float2(Qa.x - Qb.x, Qa.y - Qb.y);
        float2 v = cmul(dq, make_float2(tq.z, tq.w));
        int p = swz(2 * j);  // even; swz(2j+1) == p+1
        bufA[p] = u;
        bufA[p + 1] = v;
    }
    __syncthreads();
    r4_stage_itab<256, 2>(bufA, bufB, TW, tid);        __syncthreads();
    r4_stage_itab<64, 8>(bufB, bufA, TW + 2 * 256, tid); __syncthreads();
    r4_stage_itab<16, 32>(bufA, bufB, TW + 2 * 320, tid); __syncthreads();
    r4_stage_itab<4, 128>(bufB, bufA, TW + 2 * 336, tid); __syncthreads();
    r4_stage_itab<1, 512>(bufA, bufB, TW, tid);        __syncthreads();

    int start = trim[s * SIG];
    const float* f = (const float*)bufB;   // f view: z[2m], z[2m+1] at swz(m)
    float* orow = out + (size_t)blockIdx.x * SIG;
    #pragma unroll
    for (int n0 = 0; n0 < SIG; n0 += NT) {
        int n = n0 + tid;
        int t = start + n;
        orow[n] = f[2 * swz(t >> 1) + (t & 1)];
    }
}

// ---------------------------------------------------------------------------
extern "C" void kernel_launch(void* const* d_in, const int* in_sizes, int n_in,
                              void* d_out, int out_size, void* d_ws, size_t ws_size,
                              hipStream_t stream) {
    const float* x    = (const float*)d_in[0];
    const float* ker  = (const float*)d_in[1];
    const float* ssq  = (const float*)d_in[2];
    const int*   trim = (const int*)d_in[3];
    float*       out  = (float*)d_out;

    float2* Xf = (float2*)d_ws;                       // 512*4096 float2 = 16 MB
    float2* Kf = Xf + (size_t)NBATCH * NFFT;          // 64*4096 float2 = 2 MB
    float4* TQ = (float4*)(Kf + (size_t)NSCALES * NFFT);  // 1024 float4 = 16 KB
    float4* TW = TQ + 1024;                           // 680 float4 = 10.9 KB

    hipLaunchKernelGGL(twiddle_init, dim3(8), dim3(256), 0, stream, TQ, TW);
    hipLaunchKernelGGL(fwd_fft_x, dim3(NBATCH), dim3(NT), 0, stream, x, Xf);
    hipLaunchKernelGGL(fwd_fft_k, dim3(NSCALES), dim3(NT), 0, stream, ker, ssq, Kf);
    hipLaunchKernelGGL(conv_ifft, dim3(NBATCH * NSCALES), dim3(NT), 0, stream,
                       Xf, Kf, trim, TQ, TW, out);
}

// Round 6
// 461.304 us; speedup vs baseline: 3.7266x; 1.0115x over previous
//
#include <hip/hip_runtime.h>

#define NFFT 4096
#define SIG  2048
#define NSCALES 64
#define LMAX 1025
#define NBATCH 512
#define NT   256

// XOR swizzle on complex index: spreads strided Stockham writes across banks.
// Even XOR value: preserves pair adjacency and float4 (16B) alignment.
__device__ __forceinline__ int swz(int a) { return a ^ ((a >> 4) & 14); }

__device__ __forceinline__ float2 cmul(float2 a, float2 b) {
    return make_float2(a.x * b.x - a.y * b.y, a.x * b.y + a.y * b.x);
}
// Two packed complex (x,y),(z,w) ops:
__device__ __forceinline__ float4 add4(float4 a, float4 b) {
    return make_float4(a.x + b.x, a.y + b.y, a.z + b.z, a.w + b.w);
}
__device__ __forceinline__ float4 sub4(float4 a, float4 b) {
    return make_float4(a.x - b.x, a.y - b.y, a.z - b.z, a.w - b.w);
}
__device__ __forceinline__ float4 mulI4(float4 a) {   // both complex * (+i)
    return make_float4(-a.y, a.x, -a.w, a.z);
}
__device__ __forceinline__ float4 cmul4(float4 a, float2 w) {  // both * same w
    return make_float4(a.x * w.x - a.y * w.y, a.x * w.y + a.y * w.x,
                       a.z * w.x - a.w * w.y, a.z * w.y + a.w * w.x);
}

// ---------------------------------------------------------------------------
// Twiddle tables (global, L1/L2-resident, shared by all 32768 conv WGs):
//   TQ[j]  = (t, t^2) packed as (cos,sin,cos,sin), t = e^{2 pi i j/4096}. 16KB
//   TW[..] = per-stage (w1, w2, w3) for inverse Stockham radix-4 stages,
//            2 x float4 per entry.  Offsets: L=256 -> 0, L=64 -> 256,
//            L=16 -> 320, L=4 -> 336.  w_r = e^{+2 pi i j r/(4L)}.     11KB
// ---------------------------------------------------------------------------
#define TW_ENTRIES 340

__global__ void twiddle_init(float4* __restrict__ TQ, float4* __restrict__ TW) {
    int i = blockIdx.x * blockDim.x + threadIdx.x;
    if (i < 1024) {
        float s1, c1, s2, c2;
        sincospif(i / 2048.0f, &s1, &c1);
        sincospif(i / 1024.0f, &s2, &c2);
        TQ[i] = make_float4(c1, s1, c2, s2);
    } else if (i < 1024 + TW_ENTRIES) {
        int idx = i - 1024;
        int L, j;
        if (idx < 256)      { L = 256; j = idx; }
        else if (idx < 320) { L = 64;  j = idx - 256; }
        else if (idx < 336) { L = 16;  j = idx - 320; }
        else                { L = 4;   j = idx - 336; }
        float fL = (float)L, fj = (float)j;
        float s1, c1, s2, c2, s3, c3;
        sincospif(fj / (2.0f * fL), &s1, &c1);          // w1
        sincospif(fj / fL, &s2, &c2);                   // w2 = w1^2
        sincospif(3.0f * fj / (2.0f * fL), &s3, &c3);   // w3 = w1^3
        TW[2 * idx]     = make_float4(c1, s1, c2, s2);
        TW[2 * idx + 1] = make_float4(c3, s3, 0.0f, 0.0f);
    }
}

// ---------------------------------------------------------------------------
// Generic Stockham radix-4 stage, on-the-fly twiddles (forward kernels only).
// ---------------------------------------------------------------------------
template <int L, int M, int DIR, int NN>
__device__ __forceinline__ void r4_stage(const float2* __restrict__ src,
                                         float2* __restrict__ dst, int tid) {
    const int G = NN / 4;
    #pragma unroll
    for (int g0 = 0; g0 < G; g0 += NT) {
        int g = g0 + tid;
        int k = g & (M - 1);
        int j = g / M;
        float2 a0 = src[swz(g)];
        float2 a1 = src[swz(g + G)];
        float2 a2 = src[swz(g + 2 * G)];
        float2 a3 = src[swz(g + 3 * G)];
        float2 t0 = make_float2(a0.x + a2.x, a0.y + a2.y);
        float2 t1 = make_float2(a0.x - a2.x, a0.y - a2.y);
        float2 t2 = make_float2(a1.x + a3.x, a1.y + a3.y);
        float2 t3 = make_float2(a1.x - a3.x, a1.y - a3.y);
        float2 jt3 = make_float2(-(float)DIR * t3.y, (float)DIR * t3.x);
        float2 b0 = make_float2(t0.x + t2.x, t0.y + t2.y);
        float2 b2 = make_float2(t0.x - t2.x, t0.y - t2.y);
        float2 b1 = make_float2(t1.x + jt3.x, t1.y + jt3.y);
        float2 b3 = make_float2(t1.x - jt3.x, t1.y - jt3.y);
        float sw, cw;
        sincospif((float)DIR * (float)j * (1.0f / (2 * L)), &sw, &cw);
        float2 w1 = make_float2(cw, sw);
        float2 w2 = make_float2(cw * cw - sw * sw, 2.0f * cw * sw);
        float2 w3 = cmul(w1, w2);
        b1 = cmul(b1, w1);
        b2 = cmul(b2, w2);
        b3 = cmul(b3, w3);
        int base = k + 4 * j * M;
        dst[swz(base)]         = b0;
        dst[swz(base + M)]     = b1;
        dst[swz(base + 2 * M)] = b2;
        dst[swz(base + 3 * M)] = b3;
    }
}

// ---------------------------------------------------------------------------
// Pair-vectorized inverse Stockham radix-4 stage (NN=2048, DIR=+1).
// Thread u handles g-pair (2u, 2u+1): same j (M even) -> shared twiddles,
// float4 LDS reads/writes (swz preserves alignment).  One butterfly per
// float4 half: (x,y) = g even, (z,w) = g odd.
// ---------------------------------------------------------------------------
template <int L, int M>
__device__ __forceinline__ void r4i_pair(const float2* __restrict__ src,
                                         float2* __restrict__ dst,
                                         const float4* __restrict__ tw,
                                         int u) {
    int g = 2 * u;
    float4 a0 = *(const float4*)&src[swz(g)];
    float4 a1 = *(const float4*)&src[swz(g + 512)];
    float4 a2 = *(const float4*)&src[swz(g + 1024)];
    float4 a3 = *(const float4*)&src[swz(g + 1536)];
    float4 t0 = add4(a0, a2);
    float4 t1 = sub4(a0, a2);
    float4 t2 = add4(a1, a3);
    float4 t3 = sub4(a1, a3);
    float4 jt3 = mulI4(t3);
    float4 b0 = add4(t0, t2);
    float4 b2 = sub4(t0, t2);
    float4 b1 = add4(t1, jt3);
    float4 b3 = sub4(t1, jt3);
    int j = g / M;
    int k = g & (M - 1);
    if (L > 1) {
        float4 wa = tw[2 * j];
        float4 wb = tw[2 * j + 1];
        b1 = cmul4(b1, make_float2(wa.x, wa.y));
        b2 = cmul4(b2, make_float2(wa.z, wa.w));
        b3 = cmul4(b3, make_float2(wb.x, wb.y));
    }
    int base = k + 4 * j * M;   // even (k, M even)
    *(float4*)&dst[swz(base)]         = b0;
    *(float4*)&dst[swz(base + M)]     = b1;
    *(float4*)&dst[swz(base + 2 * M)] = b2;
    *(float4*)&dst[swz(base + 3 * M)] = b3;
}

// ---------------------------------------------------------------------------
// Forward FFT (size 4096), one real signal per WG. Xf[b][k] = DFT(x_b)[k].
// ---------------------------------------------------------------------------
__global__ __launch_bounds__(NT, 2) void fwd_fft_x(const float* __restrict__ x,
                                                   float2* __restrict__ Xf) {
    __shared__ float2 bufA[NFFT], bufB[NFFT];
    int tid = threadIdx.x;
    int b = blockIdx.x;
    #pragma unroll
    for (int i0 = 0; i0 < NFFT; i0 += NT) {
        int i = i0 + tid;
        float vr = (i < SIG) ? x[(size_t)b * SIG + i] : 0.0f;
        bufA[swz(i)] = make_float2(vr, 0.0f);
    }
    __syncthreads();
    r4_stage<1024, 1, -1, 4096>(bufA, bufB, tid); __syncthreads();
    r4_stage<256, 4, -1, 4096>(bufB, bufA, tid); __syncthreads();
    r4_stage<64, 16, -1, 4096>(bufA, bufB, tid); __syncthreads();
    r4_stage<16, 64, -1, 4096>(bufB, bufA, tid); __syncthreads();
    r4_stage<4, 256, -1, 4096>(bufA, bufB, tid); __syncthreads();
    r4_stage<1, 1024, -1, 4096>(bufB, bufA, tid); __syncthreads();
    float2* Xrow = Xf + (size_t)b * NFFT;
    #pragma unroll
    for (int i0 = 0; i0 < NFFT; i0 += NT) {
        int i = i0 + tid;
        Xrow[i] = bufA[swz(i)];
    }
}

// ---------------------------------------------------------------------------
// Forward FFT of filters with diff + irfft 1/N + (-sqrt(scale)) folded in.
// ---------------------------------------------------------------------------
__global__ __launch_bounds__(NT, 2) void fwd_fft_k(const float* __restrict__ ker,
                                                   const float* __restrict__ ssq,
                                                   float2* __restrict__ Kf) {
    __shared__ float2 bufA[NFFT], bufB[NFFT];
    int tid = threadIdx.x;
    int s = blockIdx.x;
    #pragma unroll
    for (int i0 = 0; i0 < NFFT; i0 += NT) {
        int i = i0 + tid;
        float vr = (i < LMAX) ? ker[(size_t)s * LMAX + i] : 0.0f;
        bufA[swz(i)] = make_float2(vr, 0.0f);
    }
    __syncthreads();
    r4_stage<1024, 1, -1, 4096>(bufA, bufB, tid); __syncthreads();
    r4_stage<256, 4, -1, 4096>(bufB, bufA, tid); __syncthreads();
    r4_stage<64, 16, -1, 4096>(bufA, bufB, tid); __syncthreads();
    r4_stage<16, 64, -1, 4096>(bufB, bufA, tid); __syncthreads();
    r4_stage<4, 256, -1, 4096>(bufA, bufB, tid); __syncthreads();
    r4_stage<1, 1024, -1, 4096>(bufB, bufA, tid); __syncthreads();
    float scale = -ssq[s] * (1.0f / (float)NFFT);
    float2* Krow = Kf + (size_t)s * NFFT;
    #pragma unroll
    for (int i0 = 0; i0 < NFFT; i0 += NT) {
        int i = i0 + tid;
        float sn, cs;
        sincospif((float)i * (1.0f / 2048.0f), &sn, &cs);
        float2 fac = make_float2(scale * (cs - 1.0f), scale * sn);
        Krow[i] = cmul(bufA[swz(i)], fac);
    }
}

// ---------------------------------------------------------------------------
// Pack one spectral index j: P = X*Khat at j, j+1024, j+2048, j+3072 ->
// Q[j], Q[j+1024] (real-ifft full-spectrum packing) -> fused radix-2 ->
// returns (u, v) to be stored at complex (2j, 2j+1).
// ---------------------------------------------------------------------------
__device__ __forceinline__ float4 pack_one(float2 X0, float2 X1, float2 X2,
                                           float2 X3, float2 K0, float2 K1,
                                           float2 K2, float2 K3, float4 tq) {
    float2 P0 = cmul(X0, K0);
    float2 P1 = cmul(X1, K1);
    float2 P2 = cmul(X2, K2);
    float2 P3 = cmul(X3, K3);
    float cj = tq.x, sj = tq.y;
    float2 d02 = make_float2(P0.x - P2.x, P0.y - P2.y);
    float2 itd = cmul(make_float2(-sj, cj), d02);       // (i*t)*(P0-P2)
    float2 Qa = make_float2(P0.x + P2.x + itd.x, P0.y + P2.y + itd.y);
    float2 d13 = make_float2(P1.x - P3.x, P1.y - P3.y);
    float2 td = cmul(make_float2(cj, sj), d13);
    float2 Qb = make_float2(P1.x + P3.x - td.x, P1.y + P3.y - td.y);
    float2 u = make_float2(Qa.x + Qb.x, Qa.y + Qb.y);
    float2 dq = make_float2(Qa.x - Qb.x, Qa.y - Qb.y);
    float2 v = cmul(dq, make_float2(tq.z, tq.w));       // w = t^2
    return make_float4(u.x, u.y, v.x, v.y);
}

// ---------------------------------------------------------------------------
// Per-(b,s) conv + inverse FFT.  Pack -> 4 pair-vectorized radix-4 stages ->
// final radix-4 stage fused with clipped global store (r=3 never in-window:
// start <= 511, window end start+2047 <= 2558 < 3072).
// ---------------------------------------------------------------------------
__global__ __launch_bounds__(NT, 4) void conv_ifft(const float2* __restrict__ Xf,
                                                   const float2* __restrict__ Kf,
                                                   const int* __restrict__ trim,
                                                   const float4* __restrict__ TQ,
                                                   const float4* __restrict__ TW,
                                                   float* __restrict__ out) {
    __shared__ float4 bufA4[1024], bufB4[1024];
    float2* bufA = (float2*)bufA4;
    float2* bufB = (float2*)bufB4;
    int u = threadIdx.x;
    int b = blockIdx.x >> 6;
    int s = blockIdx.x & 63;
    const float2* X = Xf + (size_t)b * NFFT;
    const float2* K = Kf + (size_t)s * NFFT;

    // Pack: thread v handles j = 2v, 2v+1 (float4 global loads).
    #pragma unroll
    for (int v0 = 0; v0 < 512; v0 += NT) {
        int v = v0 + u;
        int j = 2 * v;
        float4 Xa = *(const float4*)&X[j];
        float4 Xb = *(const float4*)&X[j + 1024];
        float4 Xc = *(const float4*)&X[j + 2048];
        float4 Xd = *(const float4*)&X[j + 3072];
        float4 Ka = *(const float4*)&K[j];
        float4 Kb = *(const float4*)&K[j + 1024];
        float4 Kc = *(const float4*)&K[j + 2048];
        float4 Kd = *(const float4*)&K[j + 3072];
        float4 r0 = pack_one(make_float2(Xa.x, Xa.y), make_float2(Xb.x, Xb.y),
                             make_float2(Xc.x, Xc.y), make_float2(Xd.x, Xd.y),
                             make_float2(Ka.x, Ka.y), make_float2(Kb.x, Kb.y),
                             make_float2(Kc.x, Kc.y), make_float2(Kd.x, Kd.y),
                             TQ[j]);
        float4 r1 = pack_one(make_float2(Xa.z, Xa.w), make_float2(Xb.z, Xb.w),
                             make_float2(Xc.z, Xc.w), make_float2(Xd.z, Xd.w),
                             make_float2(Ka.z, Ka.w), make_float2(Kb.z, Kb.w),
                             make_float2(Kc.z, Kc.w), make_float2(Kd.z, Kd.w),
                             TQ[j + 1]);
        *(float4*)&bufA[swz(2 * j)]     = r0;   // complex (2j, 2j+1)
        *(float4*)&bufA[swz(2 * j + 2)] = r1;   // complex (2j+2, 2j+3)
    }
    __syncthreads();
    r4i_pair<256, 2>(bufA, bufB, TW, u);           __syncthreads();
    r4i_pair<64, 8>(bufB, bufA, TW + 2 * 256, u);  __syncthreads();
    r4i_pair<16, 32>(bufA, bufB, TW + 2 * 320, u); __syncthreads();
    r4i_pair<4, 128>(bufB, bufA, TW + 2 * 336, u); __syncthreads();

    // Final stage (L=1, M=512, j=0, twiddle-free) fused with output store.
    {
        int g = 2 * u;
        float4 a0 = *(const float4*)&bufA[swz(g)];
        float4 a1 = *(const float4*)&bufA[swz(g + 512)];
        float4 a2 = *(const float4*)&bufA[swz(g + 1024)];
        float4 a3 = *(const float4*)&bufA[swz(g + 1536)];
        float4 t0 = add4(a0, a2);
        float4 t1 = sub4(a0, a2);
        float4 t2 = add4(a1, a3);
        float4 t3 = sub4(a1, a3);
        float4 jt3 = mulI4(t3);
        float4 b0 = add4(t0, t2);          // m = g + 0   -> f-idx 4u + 0
        float4 b1 = add4(t1, jt3);         // m = g + 512 -> f-idx 4u + 1024
        float4 b2 = sub4(t0, t2);          // m = g + 1024-> f-idx 4u + 2048
        // b3 (f-idx 4u + 3072) never inside the trim window: skip.
        int start = trim[s * SIG];
        float* orow = out + (size_t)blockIdx.x * SIG;
        float4 rs[3] = {b0, b1, b2};
        #pragma unroll
        for (int r = 0; r < 3; ++r) {
            int o = 4 * u + 1024 * r - start;
            float vals[4] = {rs[r].x, rs[r].y, rs[r].z, rs[r].w};
            #pragma unroll
            for (int e = 0; e < 4; ++e) {
                int n = o + e;
                if ((unsigned)n < (unsigned)SIG) orow[n] = vals[e];
            }
        }
    }
}

// ---------------------------------------------------------------------------
extern "C" void kernel_launch(void* const* d_in, const int* in_sizes, int n_in,
                              void* d_out, int out_size, void* d_ws, size_t ws_size,
                              hipStream_t stream) {
    const float* x    = (const float*)d_in[0];
    const float* ker  = (const float*)d_in[1];
    const float* ssq  = (const float*)d_in[2];
    const int*   trim = (const int*)d_in[3];
    float*       out  = (float*)d_out;

    float2* Xf = (float2*)d_ws;                       // 512*4096 float2 = 16 MB
    float2* Kf = Xf + (size_t)NBATCH * NFFT;          // 64*4096 float2 = 2 MB
    float4* TQ = (float4*)(Kf + (size_t)NSCALES * NFFT);  // 1024 float4 = 16 KB
    float4* TW = TQ + 1024;                           // 680 float4 = 10.9 KB

    hipLaunchKernelGGL(twiddle_init, dim3(8), dim3(256), 0, stream, TQ, TW);
    hipLaunchKernelGGL(fwd_fft_x, dim3(NBATCH), dim3(NT), 0, stream, x, Xf);
    hipLaunchKernelGGL(fwd_fft_k, dim3(NSCALES), dim3(NT), 0, stream, ker, ssq, Kf);
    hipLaunchKernelGGL(conv_ifft, dim3(NBATCH * NSCALES), dim3(NT), 0, stream,
                       Xf, Kf, trim, TQ, TW, out);
}